// Round 4
// baseline (362.447 us; speedup 1.0000x reference)
//
#include <hip/hip_runtime.h>
#include <hip/hip_bf16.h>
#include <stdint.h>

#define NN   100000
#define NE   1600000
#define KIN  256
#define FOUT 128

typedef __attribute__((ext_vector_type(8))) short short8;
typedef __attribute__((ext_vector_type(4))) float f32x4;
typedef __attribute__((ext_vector_type(2))) float f32x2;

static __device__ __forceinline__ unsigned short f2bf(float f) {
  unsigned int u = __float_as_uint(f);
  u += 0x7fffu + ((u >> 16) & 1u);   // RNE (inputs finite)
  return (unsigned short)(u >> 16);
}

static __device__ __forceinline__ short8 pack8(float4 u, float4 v) {
  short8 r;
  r[0] = (short)f2bf(u.x); r[1] = (short)f2bf(u.y);
  r[2] = (short)f2bf(u.z); r[3] = (short)f2bf(u.w);
  r[4] = (short)f2bf(v.x); r[5] = (short)f2bf(v.y);
  r[6] = (short)f2bf(v.z); r[7] = (short)f2bf(v.w);
  return r;
}

// ---------------------------------------------------------------------------
// 1) W[k][n] fp32 -> wt[which][n][k] bf16 (transposed: B-frag = 16B contig).
__global__ void convert_w(const float* __restrict__ W0, const float* __restrict__ W1,
                          unsigned short* __restrict__ wt) {
  int n = blockIdx.x;          // 0..127
  int k = threadIdx.x;         // 0..255
  int which = blockIdx.y;
  const float* W = which ? W1 : W0;
  wt[(size_t)which * (FOUT * KIN) + n * KIN + k] = f2bf(W[k * FOUT + n]);
}

// ---------------------------------------------------------------------------
// 2) rows sorted -> CSR row_ptr, linear edge scan (lower_bound semantics).
__global__ __launch_bounds__(256) void build_rowptr(const int* __restrict__ rows0,
                                                    const int* __restrict__ rows1,
                                                    int* __restrict__ rp0,
                                                    int* __restrict__ rp1) {
  const int e = blockIdx.x * 256 + threadIdx.x;       // 6250*256 == NE exactly
  const int* rows = blockIdx.y ? rows1 : rows0;
  int* rp = blockIdx.y ? rp1 : rp0;
  int r1 = rows[e];
  int r2 = (e + 1 < NE) ? rows[e + 1] : NN;
  if (e == 0)
    for (int r = 0; r <= r1; ++r) rp[r] = 0;
  for (int r = r1 + 1; r <= r2; ++r) rp[r] = e + 1;
}

// ---------------------------------------------------------------------------
// 3) Fused dual-matrix GEMM: h[t] = bf16( x @ W[t] ), t = 0,1.  (unchanged R3)
__global__ __launch_bounds__(256) void gemm_fused(const float* __restrict__ x,
                                                  const unsigned short* __restrict__ wt,
                                                  unsigned short* __restrict__ h) {
  // [buf][mat 2][col 128][k 64] bf16, 16B slots XOR-swizzled by col&7
  __shared__ __align__(16) unsigned short bbuf[2][2 * 128 * 64];   // 64 KB

  const int tid  = threadIdx.x;
  const int lane = tid & 63;
  const int wv   = tid >> 6;
  const int m    = lane & 15;
  const int quad = lane >> 4;
  const int rowbase = blockIdx.x * 128 + wv * 32;

  int r0 = rowbase + m;
  int r1 = rowbase + 16 + m;
  int r0c = r0 < NN ? r0 : NN - 1;    // clamp loads; stores masked below
  int r1c = r1 < NN ? r1 : NN - 1;
  const float* ap0 = x + (size_t)r0c * KIN + quad * 8;
  const float* ap1 = x + (size_t)r1c * KIN + quad * 8;

  f32x4 acc[2][2][8];   // [mat][rowtile][coltile]
#pragma unroll
  for (int t = 0; t < 2; ++t)
#pragma unroll
    for (int i = 0; i < 2; ++i)
#pragma unroll
      for (int n = 0; n < 8; ++n)
        acc[t][i][n] = (f32x4){0.f, 0.f, 0.f, 0.f};

  uint4 sreg[8];
#define STAGE_LOAD(ko_) do {                                                   \
    _Pragma("unroll")                                                          \
    for (int u = 0; u < 8; ++u) {                                              \
      int pid = u * 256 + tid; int tm = pid >> 10;                             \
      int c = (pid >> 3) & 127; int s = pid & 7;                               \
      sreg[u] = *(const uint4*)(wt + (size_t)tm * (FOUT * KIN) + c * KIN +     \
                                (ko_) + s * 8);                                \
    } } while (0)
#define STAGE_WRITE(buf_) do {                                                 \
    _Pragma("unroll")                                                          \
    for (int u = 0; u < 8; ++u) {                                              \
      int pid = u * 256 + tid; int tm = pid >> 10;                             \
      int c = (pid >> 3) & 127; int s = pid & 7;                               \
      *(uint4*)&bbuf[buf_][tm * 8192 + c * 64 + ((s ^ (c & 7)) * 8)] = sreg[u];\
    } } while (0)

  float4 fc[4], fn[4];
  fc[0] = *(const float4*)(ap0);     fc[1] = *(const float4*)(ap0 + 4);
  fc[2] = *(const float4*)(ap1);     fc[3] = *(const float4*)(ap1 + 4);

  STAGE_LOAD(0);
  STAGE_WRITE(0);
  __syncthreads();

#pragma unroll
  for (int ci = 0; ci < 4; ++ci) {
    if (ci < 3) STAGE_LOAD((ci + 1) * 64);
#pragma unroll
    for (int kk = 0; kk < 2; ++kk) {
      const int ki = ci * 2 + kk;
      if (ki < 7) {
        const int off = (ki + 1) * 32;
        fn[0] = *(const float4*)(ap0 + off);     fn[1] = *(const float4*)(ap0 + off + 4);
        fn[2] = *(const float4*)(ap1 + off);     fn[3] = *(const float4*)(ap1 + off + 4);
      }
      short8 a0 = pack8(fc[0], fc[1]);
      short8 a1 = pack8(fc[2], fc[3]);
      const unsigned short* bb = &bbuf[ci & 1][0];
#pragma unroll
      for (int t = 0; t < 2; ++t)
#pragma unroll
        for (int n = 0; n < 8; ++n) {
          const int col = n * 16 + m;
          short8 b = *(const short8*)(bb + t * 8192 + col * 64 +
                                      (((kk * 4 + quad) ^ (m & 7)) * 8));
          acc[t][0][n] = __builtin_amdgcn_mfma_f32_16x16x32_bf16(a0, b, acc[t][0][n], 0, 0, 0);
          acc[t][1][n] = __builtin_amdgcn_mfma_f32_16x16x32_bf16(a1, b, acc[t][1][n], 0, 0, 0);
        }
      fc[0] = fn[0]; fc[1] = fn[1]; fc[2] = fn[2]; fc[3] = fn[3];
    }
    if (ci < 3) {
      STAGE_WRITE((ci + 1) & 1);
      __syncthreads();
    }
  }
#undef STAGE_LOAD
#undef STAGE_WRITE

  unsigned short* tile = &bbuf[0][0] + wv * 4096;    // 32 rows x 128 cols
#pragma unroll
  for (int t = 0; t < 2; ++t) {
#pragma unroll
    for (int i = 0; i < 2; ++i)
#pragma unroll
      for (int n = 0; n < 8; ++n)
#pragma unroll
        for (int reg = 0; reg < 4; ++reg)
          tile[(i * 16 + quad * 4 + reg) * 128 + n * 16 + m] = f2bf(acc[t][i][n][reg]);

    unsigned short* hh = h + (size_t)t * NN * FOUT;
#pragma unroll
    for (int p = 0; p < 8; ++p) {
      int row = p * 4 + quad;                        // 0..31
      uint4 v = *(const uint4*)&tile[row * 128 + m * 8];
      int grow = rowbase + row;
      if (grow < NN)
        *(uint4*)&hh[(size_t)grow * FOUT + m * 8] = v;
    }
  }
}

// ---------------------------------------------------------------------------
// 4) Fused SpMM + relu, v2: locality-engineered random gather.
//    R3 counters: FETCH 407MB vs 819MB logical gather -> 50% of h-gathers
//    miss to HBM because access order is temporally random over all 51MB.
//    Fix: (a) per row, bitonic-sort (col,val) in registers by col and walk
//    edges in ascending col order (readlane broadcast, no scratch mem);
//    (b) persistent lockstep grid (2048 blocks = 8/CU fully co-resident,
//    grid-stride rows) so ALL concurrent waves gather in the same sliding
//    col window -> gathers hit L2/L3; HBM drops to compulsory traffic.
static __device__ __forceinline__ void bitonic64(int lane, int& c, unsigned& v) {
#pragma unroll
  for (int k = 2; k <= 64; k <<= 1) {
#pragma unroll
    for (int j = k >> 1; j > 0; j >>= 1) {
      int oc = __shfl_xor(c, j, 64);
      int ov = __shfl_xor((int)v, j, 64);
      bool keepmin = ((lane & k) == 0) == ((lane & j) == 0);
      bool take = keepmin ? (oc < c) : (oc > c);
      if (take) { c = oc; v = (unsigned)ov; }
    }
  }
}

static __device__ __forceinline__ float rl_f(unsigned v, int idx) {
  return __uint_as_float((unsigned)__builtin_amdgcn_readlane((int)v, idx));
}

// sorted-register tail: consume [p, d) one mat
static __device__ __forceinline__ void tail_sorted(int cs, unsigned vs, int p, int d,
                                                   const unsigned short* __restrict__ hsrc,
                                                   int fo, float& sx, float& sy) {
  for (; p + 4 <= d; p += 4) {
    unsigned g[4];
#pragma unroll
    for (int u = 0; u < 4; ++u) {
      int c = __builtin_amdgcn_readlane(cs, p + u);
      g[u] = *(const unsigned*)(hsrc + (size_t)c * FOUT + fo);
    }
#pragma unroll
    for (int u = 0; u < 4; ++u) {
      float v = rl_f(vs, p + u);
      sx += v * __uint_as_float(g[u] << 16);
      sy += v * __uint_as_float(g[u] & 0xffff0000u);
    }
  }
  for (; p < d; ++p) {
    int c = __builtin_amdgcn_readlane(cs, p);
    float v = rl_f(vs, p);
    unsigned g = *(const unsigned*)(hsrc + (size_t)c * FOUT + fo);
    sx += v * __uint_as_float(g << 16);
    sy += v * __uint_as_float(g & 0xffff0000u);
  }
}

// fallback (deg > 64, statistically never): old scalar path
static __device__ __forceinline__ void tail_spmm(const int* __restrict__ cols,
                                                 const float* __restrict__ vals,
                                                 const unsigned short* __restrict__ hsrc,
                                                 int i, int e, int fo,
                                                 float& sx, float& sy) {
  for (; i < e; ++i) {
    int c = cols[i];
    float v = vals[i];
    unsigned g = *(const unsigned*)(hsrc + (size_t)c * FOUT + fo);
    sx += v * __uint_as_float(g << 16);
    sy += v * __uint_as_float(g & 0xffff0000u);
  }
}

__global__ __launch_bounds__(256, 8) void spmm_relu(
    const int* __restrict__ rp0, const int* __restrict__ cols0, const float* __restrict__ vals0,
    const int* __restrict__ rp1, const int* __restrict__ cols1, const float* __restrict__ vals1,
    const unsigned short* __restrict__ h, float* __restrict__ out) {
  const int lane = threadIdx.x & 63;
  const int wgid = blockIdx.x * 4 + (threadIdx.x >> 6);   // 0..8191 (grid 2048)
  const int fo = lane * 2;

  const unsigned short* h0 = h;
  const unsigned short* h1 = h + (size_t)NN * FOUT;

  for (int rr = wgid; rr < NN; rr += 8192) {
    const int r = __builtin_amdgcn_readfirstlane(rr);

    int i0 = __builtin_amdgcn_readfirstlane(rp0[r]);
    int e0 = __builtin_amdgcn_readfirstlane(rp0[r + 1]);
    int i1 = __builtin_amdgcn_readfirstlane(rp1[r]);
    int e1 = __builtin_amdgcn_readfirstlane(rp1[r + 1]);
    const int d0 = e0 - i0, d1 = e1 - i1;

    float sx = 0.f, sy = 0.f;

    if (d0 <= 64 && d1 <= 64) {
      // lane-parallel edge load + in-register col-sort, both matrices
      int c0s = 0x7fffffff, c1s = 0x7fffffff;
      unsigned vb0 = 0, vb1 = 0;
      if (lane < d0) {
        c0s = cols0[i0 + lane];
        vb0 = __float_as_uint(vals0[i0 + lane]);
      }
      if (lane < d1) {
        c1s = cols1[i1 + lane];
        vb1 = __float_as_uint(vals1[i1 + lane]);
      }
      bitonic64(lane, c0s, vb0);
      bitonic64(lane, c1s, vb1);

      int p0 = 0, p1 = 0;
      // main: dual-matrix batches, 16 gathers in flight, ascending col order
      while (p0 + 8 <= d0 && p1 + 8 <= d1) {
        unsigned g0[8], g1[8];
#pragma unroll
        for (int u = 0; u < 8; ++u) {
          int c = __builtin_amdgcn_readlane(c0s, p0 + u);
          g0[u] = *(const unsigned*)(h0 + (size_t)c * FOUT + fo);
        }
#pragma unroll
        for (int u = 0; u < 8; ++u) {
          int c = __builtin_amdgcn_readlane(c1s, p1 + u);
          g1[u] = *(const unsigned*)(h1 + (size_t)c * FOUT + fo);
        }
#pragma unroll
        for (int u = 0; u < 8; ++u) {
          float v = rl_f(vb0, p0 + u);
          sx += v * __uint_as_float(g0[u] << 16);
          sy += v * __uint_as_float(g0[u] & 0xffff0000u);
        }
#pragma unroll
        for (int u = 0; u < 8; ++u) {
          float v = rl_f(vb1, p1 + u);
          sx += v * __uint_as_float(g1[u] << 16);
          sy += v * __uint_as_float(g1[u] & 0xffff0000u);
        }
        p0 += 8;
        p1 += 8;
      }
      tail_sorted(c0s, vb0, p0, d0, h0, fo, sx, sy);
      tail_sorted(c1s, vb1, p1, d1, h1, fo, sx, sy);
    } else {
      tail_spmm(cols0, vals0, h0, i0, e0, fo, sx, sy);
      tail_spmm(cols1, vals1, h1, i1, e1, fo, sx, sy);
    }

    f32x2 o;
    o.x = sx > 0.f ? sx : 0.f;
    o.y = sy > 0.f ? sy : 0.f;
    __builtin_nontemporal_store(o, (f32x2*)(out + (size_t)r * FOUT + fo));
  }
}

// ---------------------------------------------------------------------------
extern "C" void kernel_launch(void* const* d_in, const int* in_sizes, int n_in,
                              void* d_out, int out_size, void* d_ws, size_t ws_size,
                              hipStream_t stream) {
  const float* x     = (const float*)d_in[0];
  const int*   rows0 = (const int*)d_in[1];
  const int*   cols0 = (const int*)d_in[2];
  const float* vals0 = (const float*)d_in[3];
  const int*   rows1 = (const int*)d_in[4];
  const int*   cols1 = (const int*)d_in[5];
  const float* vals1 = (const float*)d_in[6];
  const float* W0    = (const float*)d_in[7];
  const float* W1    = (const float*)d_in[8];
  float* out = (float*)d_out;

  // ws layout (16B aligned):
  //   wt  : 2*128*256 bf16 =    131,072 B @ 0
  //   h   : 2*NN*128 bf16  = 51,200,000 B @ 131,072
  //   rp0 : (NN+1) i32     @ 51,331,072
  //   rp1 : (NN+1) i32     @ 51,731,136
  char* ws = (char*)d_ws;
  unsigned short* wt = (unsigned short*)(ws);
  unsigned short* h  = (unsigned short*)(ws + 131072);
  int* rp0 = (int*)(ws + 51331072);
  int* rp1 = (int*)(ws + 51731136);

  build_rowptr<<<dim3(6250, 2), 256, 0, stream>>>(rows0, rows1, rp0, rp1);
  convert_w<<<dim3(128, 2), 256, 0, stream>>>(W0, W1, wt);
  gemm_fused<<<dim3((NN + 127) / 128, 1), 256, 0, stream>>>(x, wt, h);
  spmm_relu<<<2048, 256, 0, stream>>>(rp0, cols0, vals0, rp1, cols1, vals1, h, out);
}

// Round 5
// 328.957 us; speedup vs baseline: 1.1018x; 1.1018x over previous
//
#include <hip/hip_runtime.h>
#include <hip/hip_bf16.h>
#include <stdint.h>

#define NN   100000
#define NE   1600000
#define KIN  256
#define FOUT 128

typedef __attribute__((ext_vector_type(8))) short short8;
typedef __attribute__((ext_vector_type(4))) float f32x4;
typedef __attribute__((ext_vector_type(2))) float f32x2;

static __device__ __forceinline__ unsigned short f2bf(float f) {
  unsigned int u = __float_as_uint(f);
  u += 0x7fffu + ((u >> 16) & 1u);   // RNE (inputs finite)
  return (unsigned short)(u >> 16);
}

static __device__ __forceinline__ short8 pack8(float4 u, float4 v) {
  short8 r;
  r[0] = (short)f2bf(u.x); r[1] = (short)f2bf(u.y);
  r[2] = (short)f2bf(u.z); r[3] = (short)f2bf(u.w);
  r[4] = (short)f2bf(v.x); r[5] = (short)f2bf(v.y);
  r[6] = (short)f2bf(v.z); r[7] = (short)f2bf(v.w);
  return r;
}

// ---------------------------------------------------------------------------
// 1) W[k][n] fp32 -> wt[which][n][k] bf16 (transposed: B-frag = 16B contig).
__global__ void convert_w(const float* __restrict__ W0, const float* __restrict__ W1,
                          unsigned short* __restrict__ wt) {
  int n = blockIdx.x;          // 0..127
  int k = threadIdx.x;         // 0..255
  int which = blockIdx.y;
  const float* W = which ? W1 : W0;
  wt[(size_t)which * (FOUT * KIN) + n * KIN + k] = f2bf(W[k * FOUT + n]);
}

// ---------------------------------------------------------------------------
// 2) rows sorted -> CSR row_ptr, linear edge scan (lower_bound semantics).
__global__ __launch_bounds__(256) void build_rowptr(const int* __restrict__ rows0,
                                                    const int* __restrict__ rows1,
                                                    int* __restrict__ rp0,
                                                    int* __restrict__ rp1) {
  const int e = blockIdx.x * 256 + threadIdx.x;       // 6250*256 == NE exactly
  const int* rows = blockIdx.y ? rows1 : rows0;
  int* rp = blockIdx.y ? rp1 : rp0;
  int r1 = rows[e];
  int r2 = (e + 1 < NE) ? rows[e + 1] : NN;
  if (e == 0)
    for (int r = 0; r <= r1; ++r) rp[r] = 0;
  for (int r = r1 + 1; r <= r2; ++r) rp[r] = e + 1;
}

// ---------------------------------------------------------------------------
// 3) Fused dual-matrix GEMM v3: h[t] = bf16( x @ W[t] ), t = 0,1.
//    R4 analysis: gemm ~84us vs ~25us floor, latency-bound at 8 waves/CU
//    (64KB LDS + ~200 VGPR reg-staging). v3: 512-thr blocks, 8 waves x
//    16 rows; wave tile 16x128x2mats -> acc 64 VGPR. B staged via
//    global_load_lds width=16 (linear LDS dest, XOR-8 swizzle applied to
//    the GLOBAL source address; read side identical to R3 -> conflict-free
//    ds_read_b128). No sreg/ds_write -> ~110 VGPR; launch_bounds(512,4)
//    -> 4 waves/SIMD = 16 waves/CU (2 blocks x 64KB LDS = 128/160KB).
__global__ __launch_bounds__(512, 4) void gemm_fused(const float* __restrict__ x,
                                                     const unsigned short* __restrict__ wt,
                                                     unsigned short* __restrict__ h) {
  // [buf][mat 2][col 128][slot 8] 16B slots; LDS layout LINEAR (DMA dest),
  // swizzle lives in the global source: LDS[mat][col][s] = global slot s^(col&7)
  __shared__ __align__(16) unsigned short bbuf[2][2 * 128 * 64];   // 64 KB

  const int tid  = threadIdx.x;      // 0..511
  const int lane = tid & 63;
  const int wv   = tid >> 6;         // 0..7
  const int m    = lane & 15;
  const int quad = lane >> 4;
  const int rowbase = blockIdx.x * 128 + wv * 16;

  int r  = rowbase + m;
  int rc = r < NN ? r : NN - 1;      // clamp loads; stores masked below
  const float* ap = x + (size_t)rc * KIN + quad * 8;

  f32x4 acc[2][8];   // [mat][coltile]
#pragma unroll
  for (int t = 0; t < 2; ++t)
#pragma unroll
    for (int n = 0; n < 8; ++n)
      acc[t][n] = (f32x4){0.f, 0.f, 0.f, 0.f};

  // DMA staging: piece pid = u*512 + tid -> mat = pid>>10, col = (pid>>3)&127,
  // s = pid&7. Global: 16B at wt[mat][col][ko + (s^(col&7))*8]; LDS: linear
  // slot pid (wave-uniform base + lane*16, hardware rule).
#define STAGE_DMA(ko_, buf_) do {                                              \
    _Pragma("unroll")                                                          \
    for (int u = 0; u < 4; ++u) {                                              \
      int pid = u * 512 + tid;                                                 \
      int tm = pid >> 10; int c = (pid >> 3) & 127; int s = pid & 7;           \
      const unsigned short* g = wt + (size_t)tm * (FOUT * KIN) + c * KIN +     \
                                (ko_) + ((s ^ (c & 7)) * 8);                   \
      __builtin_amdgcn_global_load_lds(                                        \
          (const __attribute__((address_space(1))) void*)g,                    \
          (__attribute__((address_space(3))) void*)                            \
              &bbuf[buf_][(size_t)(u * 512 + wv * 64) * 8],                    \
          16, 0, 0);                                                           \
    } } while (0)

  // A pipeline: fc = current K-iter (32 k), fn = next
  float4 fc0 = *(const float4*)(ap);
  float4 fc1 = *(const float4*)(ap + 4);

  STAGE_DMA(0, 0);
  __syncthreads();

#pragma unroll
  for (int ci = 0; ci < 4; ++ci) {
    if (ci < 3) STAGE_DMA((ci + 1) * 64, (ci + 1) & 1);
#pragma unroll
    for (int kk = 0; kk < 2; ++kk) {
      const int ki = ci * 2 + kk;
      float4 fn0, fn1;
      if (ki < 7) {
        fn0 = *(const float4*)(ap + (ki + 1) * 32);
        fn1 = *(const float4*)(ap + (ki + 1) * 32 + 4);
      }
      short8 a = pack8(fc0, fc1);
      const unsigned short* bb = &bbuf[ci & 1][0];
#pragma unroll
      for (int t = 0; t < 2; ++t)
#pragma unroll
        for (int n = 0; n < 8; ++n) {
          const int col = n * 16 + m;
          short8 b = *(const short8*)(bb + t * 8192 + col * 64 +
                                      (((kk * 4 + quad) ^ (m & 7)) * 8));
          acc[t][n] = __builtin_amdgcn_mfma_f32_16x16x32_bf16(a, b, acc[t][n], 0, 0, 0);
        }
      fc0 = fn0; fc1 = fn1;
    }
    if (ci < 3) __syncthreads();   // drains DMA vmcnt + all waves' buf reads
  }
#undef STAGE_DMA

  // Epilogue: wave-private staging in bbuf[0] (all waves passed the ci=2-end
  // barrier -> finished reading bbuf[0]; ci=3 reads only bbuf[1]; regions
  // below are wave-private). 8 waves x 4KB = 32KB.
  unsigned short* tile = &bbuf[0][0] + wv * 2048;    // 16 rows x 128 cols
#pragma unroll
  for (int t = 0; t < 2; ++t) {
    // D layout: col = lane&15 (=m), row = quad*4 + reg  [m89/m91 verified]
#pragma unroll
    for (int n = 0; n < 8; ++n)
#pragma unroll
      for (int reg = 0; reg < 4; ++reg)
        tile[(quad * 4 + reg) * 128 + n * 16 + m] = f2bf(acc[t][n][reg]);

    unsigned short* hh = h + (size_t)t * NN * FOUT;
#pragma unroll
    for (int p = 0; p < 4; ++p) {
      int row = p * 4 + quad;                        // 0..15
      uint4 v = *(const uint4*)&tile[row * 128 + m * 8];
      int grow = rowbase + row;
      if (grow < NN)
        *(uint4*)&hh[(size_t)grow * FOUT + m * 8] = v;
    }
  }
}

// ---------------------------------------------------------------------------
// 4) Fused SpMM + relu (reverted to R3 version, 124.8us measured).
//    One wave per row; lane = 2 features (256B/edge coalesced gather).
//    Main loop issues 8 gathers for BOTH matrices (16 outstanding) before
//    consuming either; unroll-4 tails. Edge metadata scalarized. NT store.
static __device__ __forceinline__ void consume8(const float* __restrict__ vals, int i,
                                                const unsigned* g, float& sx, float& sy) {
#pragma unroll
  for (int u = 0; u < 8; ++u) {
    float v = vals[i + u];
    sx += v * __uint_as_float(g[u] << 16);
    sy += v * __uint_as_float(g[u] & 0xffff0000u);
  }
}

static __device__ __forceinline__ void tail_spmm(const int* __restrict__ cols,
                                                 const float* __restrict__ vals,
                                                 const unsigned short* __restrict__ hsrc,
                                                 int i, int e, int fo,
                                                 float& sx, float& sy) {
  for (; i + 4 <= e; i += 4) {
    int c0 = cols[i], c1 = cols[i + 1], c2 = cols[i + 2], c3 = cols[i + 3];
    unsigned g0 = *(const unsigned*)(hsrc + (size_t)c0 * FOUT + fo);
    unsigned g1 = *(const unsigned*)(hsrc + (size_t)c1 * FOUT + fo);
    unsigned g2 = *(const unsigned*)(hsrc + (size_t)c2 * FOUT + fo);
    unsigned g3 = *(const unsigned*)(hsrc + (size_t)c3 * FOUT + fo);
    float v0 = vals[i], v1 = vals[i + 1], v2 = vals[i + 2], v3 = vals[i + 3];
    sx += v0 * __uint_as_float(g0 << 16);
    sy += v0 * __uint_as_float(g0 & 0xffff0000u);
    sx += v1 * __uint_as_float(g1 << 16);
    sy += v1 * __uint_as_float(g1 & 0xffff0000u);
    sx += v2 * __uint_as_float(g2 << 16);
    sy += v2 * __uint_as_float(g2 & 0xffff0000u);
    sx += v3 * __uint_as_float(g3 << 16);
    sy += v3 * __uint_as_float(g3 & 0xffff0000u);
  }
  for (; i < e; ++i) {
    int c = cols[i];
    float v = vals[i];
    unsigned g = *(const unsigned*)(hsrc + (size_t)c * FOUT + fo);
    sx += v * __uint_as_float(g << 16);
    sy += v * __uint_as_float(g & 0xffff0000u);
  }
}

__global__ __launch_bounds__(256) void spmm_relu(
    const int* __restrict__ rp0, const int* __restrict__ cols0, const float* __restrict__ vals0,
    const int* __restrict__ rp1, const int* __restrict__ cols1, const float* __restrict__ vals1,
    const unsigned short* __restrict__ h, float* __restrict__ out) {
  const int lane = threadIdx.x & 63;
  int r = blockIdx.x * 4 + (threadIdx.x >> 6);   // 25000*4 == NN exactly
  r = __builtin_amdgcn_readfirstlane(r);
  const int fo = lane * 2;

  const unsigned short* h0 = h;
  const unsigned short* h1 = h + (size_t)NN * FOUT;

  int i0 = __builtin_amdgcn_readfirstlane(rp0[r]);
  int e0 = __builtin_amdgcn_readfirstlane(rp0[r + 1]);
  int i1 = __builtin_amdgcn_readfirstlane(rp1[r]);
  int e1 = __builtin_amdgcn_readfirstlane(rp1[r + 1]);

  float sx = 0.f, sy = 0.f;

  // Main: dual-matrix batches, 16 gathers in flight.
  while (i0 + 8 <= e0 && i1 + 8 <= e1) {
    unsigned g0[8], g1[8];
#pragma unroll
    for (int u = 0; u < 8; ++u) {
      int c = cols0[i0 + u];                     // uniform -> s_load
      g0[u] = *(const unsigned*)(h0 + (size_t)c * FOUT + fo);
    }
#pragma unroll
    for (int u = 0; u < 8; ++u) {
      int c = cols1[i1 + u];
      g1[u] = *(const unsigned*)(h1 + (size_t)c * FOUT + fo);
    }
    consume8(vals0, i0, g0, sx, sy);
    consume8(vals1, i1, g1, sx, sy);
    i0 += 8;
    i1 += 8;
  }
  tail_spmm(cols0, vals0, h0, i0, e0, fo, sx, sy);
  tail_spmm(cols1, vals1, h1, i1, e1, fo, sx, sy);

  f32x2 o;
  o.x = sx > 0.f ? sx : 0.f;
  o.y = sy > 0.f ? sy : 0.f;
  __builtin_nontemporal_store(o, (f32x2*)(out + (size_t)r * FOUT + fo));
}

// ---------------------------------------------------------------------------
extern "C" void kernel_launch(void* const* d_in, const int* in_sizes, int n_in,
                              void* d_out, int out_size, void* d_ws, size_t ws_size,
                              hipStream_t stream) {
  const float* x     = (const float*)d_in[0];
  const int*   rows0 = (const int*)d_in[1];
  const int*   cols0 = (const int*)d_in[2];
  const float* vals0 = (const float*)d_in[3];
  const int*   rows1 = (const int*)d_in[4];
  const int*   cols1 = (const int*)d_in[5];
  const float* vals1 = (const float*)d_in[6];
  const float* W0    = (const float*)d_in[7];
  const float* W1    = (const float*)d_in[8];
  float* out = (float*)d_out;

  // ws layout (16B aligned):
  //   wt  : 2*128*256 bf16 =    131,072 B @ 0
  //   h   : 2*NN*128 bf16  = 51,200,000 B @ 131,072
  //   rp0 : (NN+1) i32     @ 51,331,072
  //   rp1 : (NN+1) i32     @ 51,731,136
  char* ws = (char*)d_ws;
  unsigned short* wt = (unsigned short*)(ws);
  unsigned short* h  = (unsigned short*)(ws + 131072);
  int* rp0 = (int*)(ws + 51331072);
  int* rp1 = (int*)(ws + 51731136);

  build_rowptr<<<dim3(6250, 2), 256, 0, stream>>>(rows0, rows1, rp0, rp1);
  convert_w<<<dim3(128, 2), 256, 0, stream>>>(W0, W1, wt);
  gemm_fused<<<dim3((NN + 127) / 128, 1), 512, 0, stream>>>(x, wt, h);
  spmm_relu<<<25000, 256, 0, stream>>>(rp0, cols0, vals0, rp1, cols1, vals1, h, out);
}